// Round 6
// baseline (23.878 us; speedup 1.0000x reference)
//
#include <hip/hip_runtime.h>
#include <cfloat>

#define TPB 64          // TOKENS_PER_BLOCK
#define SCPB 4          // SUB_CHUNK_PER_BLOCK
#define TPSC 16         // TOKENS_PER_SUB_CHUNK

typedef float vfloat4 __attribute__((ext_vector_type(4)));

// Static load-balancing remap: work item = half-chunk (16 tokens x 4 heads),
// 128 threads per item. Block = 1024 threads = 8 item slots; block g handles
// items g + GRID*s (s=0..7) — strided interleave so active (valid) items
// spread ~uniformly across CUs regardless of where sequence ends fall.
__global__ __launch_bounds__(1024) void paged_minmax_kernel(
    const float* __restrict__ keys,
    const int* __restrict__ block_tables,
    const int* __restrict__ cu_seqlens,
    const int* __restrict__ heads_idx,
    float* __restrict__ out,
    int B, int MB, int H, int D, int Hp, int grid)
{
    const int n_chunks = MB * SCPB;

    const int tid  = threadIdx.x;
    const int s    = tid >> 7;               // item slot 0..7
    const int t128 = tid & 127;
    const int hl   = t128 >> 5;              // head within half, 0..3
    const int d4   = t128 & 31;              // float4 index within D

    const int item = blockIdx.x + grid * s;  // 0 .. B*n_chunks*2-1
    const int c    = item >> 1;              // global chunk id, 0..B*n_chunks-1
    const int half = item & 1;

    const int b  = c / n_chunks;
    const int cl = c - b * n_chunks;         // chunk within batch row

    const int h = half * (Hp >> 1) + hl;     // head 0..7

    // Early index loads — every main load's address depends on hp and blk.
    const int hp  = heads_idx[h];
    const int blk = block_tables[b * MB + (cl >> 2)];
    const int len = cu_seqlens[b + 1] - cu_seqlens[b];

    int nv = len - cl * TPSC;
    if (nv > TPSC) nv = TPSC;

    const size_t s_stride = (size_t)B * n_chunks * Hp * D;   // min->max offset
    float* out_min = out + ((size_t)b * n_chunks + cl) * (size_t)(Hp * D)
                         + (size_t)h * D + (size_t)d4 * 4;
    float* out_max = out_min + s_stride;

    if (nv <= 0) {
        vfloat4 z = (vfloat4)0.f;
        __builtin_nontemporal_store(z, reinterpret_cast<vfloat4*>(out_min));
        __builtin_nontemporal_store(z, reinterpret_cast<vfloat4*>(out_max));
        return;
    }

    const int t0 = (cl & (SCPB - 1)) * TPSC;

    const vfloat4* src = reinterpret_cast<const vfloat4*>(
        keys + ((size_t)blk * TPB + t0) * (size_t)(H * D) + (size_t)hp * D) + d4;
    const int tstride = (H * D) >> 2;        // vfloat4 units between tokens

    vfloat4 x0 = src[0];
    vfloat4 mn0 = x0, mx0 = x0;

    if (nv == TPSC) {
        // common case: all 16 loads independent; two accumulator chains
        vfloat4 x1 = src[tstride];
        vfloat4 mn1 = x1, mx1 = x1;
        #pragma unroll
        for (int t = 2; t < TPSC; t += 2) {
            vfloat4 a  = src[(size_t)t * tstride];
            vfloat4 bq = src[(size_t)(t + 1) * tstride];
            mn0 = __builtin_elementwise_min(mn0, a);
            mx0 = __builtin_elementwise_max(mx0, a);
            mn1 = __builtin_elementwise_min(mn1, bq);
            mx1 = __builtin_elementwise_max(mx1, bq);
        }
        mn0 = __builtin_elementwise_min(mn0, mn1);
        mx0 = __builtin_elementwise_max(mx0, mx1);
    } else {
        for (int t = 1; t < nv; ++t) {
            vfloat4 a = src[(size_t)t * tstride];
            mn0 = __builtin_elementwise_min(mn0, a);
            mx0 = __builtin_elementwise_max(mx0, a);
        }
    }

    __builtin_nontemporal_store(mn0, reinterpret_cast<vfloat4*>(out_min));
    __builtin_nontemporal_store(mx0, reinterpret_cast<vfloat4*>(out_max));
}

extern "C" void kernel_launch(void* const* d_in, const int* in_sizes, int n_in,
                              void* d_out, int out_size, void* d_ws, size_t ws_size,
                              hipStream_t stream) {
    const float* keys        = (const float*)d_in[0];
    const int*   block_tables= (const int*)d_in[1];
    const int*   cu_seqlens  = (const int*)d_in[2];
    const int*   heads_idx   = (const int*)d_in[3];
    float* out = (float*)d_out;

    const int B  = in_sizes[2] - 1;                 // 4
    const int MB = in_sizes[1] / B;                 // 128
    const int Hp = in_sizes[3];                     // 8
    const int D  = 128;
    const long long num_blocks_tokens = (long long)in_sizes[1] * TPB; // B*MB*64
    const int H  = (int)((long long)in_sizes[0] / num_blocks_tokens / D); // 8

    const int n_chunks = MB * SCPB;
    const int n_items  = B * n_chunks * 2;          // half-chunks: 4096
    const int threads  = 1024;                      // 8 items / block
    const int grid     = n_items / 8;               // 512

    paged_minmax_kernel<<<grid, threads, 0, stream>>>(
        keys, block_tables, cu_seqlens, heads_idx, out, B, MB, H, D, Hp, grid);
}